// Round 1
// baseline (5194.909 us; speedup 1.0000x reference)
//
#include <hip/hip_runtime.h>
#include <stdint.h>

// RBM CD-k (k=5) fused kernel for MI355X.
// Block = 64 chains (lane = chain), 4 waves (wave = slice of hidden/visible units).
// W staged once in LDS f32 [88][152] (cols 150,151 zero); all W reads are
// wave-uniform broadcast float4. Binary states packed as bits in LDS byte rows.
// RNG: lowbias32 hash of unique 30-bit counters (statistically equivalent to
// jax threefry for these chain-averaged scalar outputs).

#define NV 88
#define NH 150
#define NR 100
#define NBT (128*2048)
#define CPB 64
#define NBLK (NBT/CPB)   // 4096
#define WPAD 152

__device__ __forceinline__ uint32_t hash32(uint32_t x) {
  x ^= x >> 16; x *= 0x7feb352dU;
  x ^= x >> 15; x *= 0x846ca68bU;
  x ^= x >> 16;
  return x;
}
__device__ __forceinline__ float rng_u(uint32_t seed) {
  return (float)(hash32(seed) >> 8) * (1.0f/16777216.0f);
}
__device__ __forceinline__ float sigmoid_fast(float x) {
  return __fdividef(1.0f, 1.0f + __expf(-x));
}

// pre[0..39] = bhreg + (bits(vrow) @ W[:, JLO:JLO+40])
__device__ __forceinline__ void hidden_matvec(
    const float (*Wlp)[WPAD], const uint32_t* vrow32,
    const float* bhreg, float* pre, int JLO, int NG)
{
  uint32_t r0 = vrow32[0], r1 = vrow32[1], r2 = vrow32[2];
  #pragma unroll
  for (int jj = 0; jj < 40; ++jj) pre[jj] = bhreg[jj];
  #pragma unroll
  for (int wi = 0; wi < 3; ++wi) {
    const uint32_t word = (wi == 0) ? r0 : ((wi == 1) ? r1 : r2);
    const int nb = (wi == 2) ? 24 : 32;
    for (int b = 0; b < nb; ++b) {
      float f = (float)((word >> b) & 1u);
      const float* row = &Wlp[wi*32 + b][JLO];
      #pragma unroll
      for (int jg = 0; jg < 10; ++jg) {
        if (jg < NG) {
          const float4 w4 = *(const float4*)(row + 4*jg);
          pre[4*jg+0] = fmaf(f, w4.x, pre[4*jg+0]);
          pre[4*jg+1] = fmaf(f, w4.y, pre[4*jg+1]);
          pre[4*jg+2] = fmaf(f, w4.z, pre[4*jg+2]);
          pre[4*jg+3] = fmaf(f, w4.w, pre[4*jg+3]);
        }
      }
    }
  }
}

// pre[0..23] = bvreg + (bits(hrow, 150) @ W[VLO:VLO+24, :]^T)
__device__ __forceinline__ void visible_matvec(
    const float (*Wlp)[WPAD], const uint32_t* hrow32,
    const float* bvreg, float* pre, int VLO, int NVt)
{
  #pragma unroll
  for (int vv = 0; vv < 24; ++vv) pre[vv] = bvreg[vv];
  for (int wi = 0; wi < 5; ++wi) {     // rolled: keeps code size sane
    const uint32_t word = hrow32[wi];  // bits for j in [32*wi, 32*wi+32); j>=150 are 0
    float h[32];
    #pragma unroll
    for (int b = 0; b < 32; ++b) h[b] = (float)((word >> b) & 1u);
    const int NG8 = (wi == 4) ? 6 : 8; // wi==4: j up to 151 (cols 150/151 are zero-padded)
    #pragma unroll
    for (int vv = 0; vv < 24; ++vv) {
      if (vv < NVt) {
        const float* row = &Wlp[VLO + vv][wi*32];
        float acc = pre[vv];
        #pragma unroll
        for (int g = 0; g < 8; ++g) {
          if (g < NG8) {
            const float4 w4 = *(const float4*)(row + 4*g);
            acc = fmaf(h[4*g+0], w4.x, acc);
            acc = fmaf(h[4*g+1], w4.y, acc);
            acc = fmaf(h[4*g+2], w4.z, acc);
            acc = fmaf(h[4*g+3], w4.w, acc);
          }
        }
        pre[vv] = acc;
      }
    }
  }
}

__global__ __launch_bounds__(256, 2) void rbm_cdk_kernel(
    const float* __restrict__ padded, const float* __restrict__ mask,
    const float* __restrict__ lstm,   const float* __restrict__ W,
    const float* __restrict__ bv,     const float* __restrict__ bh,
    const float* __restrict__ Wyv,    const float* __restrict__ Wyh,
    const int*  __restrict__ kptr,    float* __restrict__ wsf)
{
  __shared__ float    Wl[NV][WPAD];      // 53.5 KB
  __shared__ uint32_t Hb32[CPB][5];      // 150 h-bits / chain (bits >=150 written 0)
  __shared__ uint32_t Vb32[CPB][3];      // 88 v-bits / chain
  __shared__ uint32_t Pb32[CPB][3];      // padded bits / chain
  __shared__ float reda[4], redb[4], redm[4];

  const int tid  = threadIdx.x;
  const int lane = tid & 63;
  const int w    = tid >> 6;
  const int C    = blockIdx.x * CPB + lane;   // global chain id, < 2^18
  const int k    = kptr[0];

  const int JLO = w * 40;                 // hidden slice
  const int NJ  = (w == 3) ? 30 : 40;
  const int NGH = (w == 3) ? 8  : 10;
  const int VLO = w * 24;                 // visible slice
  const int NVt = (w == 3) ? 16 : 24;

  // ---- stage W (zero-pad cols 150,151) ----
  for (int idx = tid; idx < NV*WPAD; idx += 256) {
    int r = idx / WPAD, c = idx - r*WPAD;
    Wl[r][c] = (c < NH) ? W[r*NH + c] : 0.0f;
  }

  // ---- stage padded bits (P) and init V = P ----
  {
    uint32_t bits = 0;
    const float4* p4 = (const float4*)(padded + (size_t)C * NV + VLO);
    #pragma unroll
    for (int g = 0; g < 6; ++g) {
      if (g*4 < NVt) {
        float4 f = p4[g];
        bits |= (f.x > 0.5f ? 1u : 0u) << (4*g+0);
        bits |= (f.y > 0.5f ? 1u : 0u) << (4*g+1);
        bits |= (f.z > 0.5f ? 1u : 0u) << (4*g+2);
        bits |= (f.w > 0.5f ? 1u : 0u) << (4*g+3);
      }
    }
    uint8_t* pb = (uint8_t*)&Pb32[lane][0];
    uint8_t* vb = (uint8_t*)&Vb32[lane][0];
    pb[3*w+0] = (uint8_t)bits; pb[3*w+1] = (uint8_t)(bits>>8); pb[3*w+2] = (uint8_t)(bits>>16);
    vb[3*w+0] = (uint8_t)bits; vb[3*w+1] = (uint8_t)(bits>>8); vb[3*w+2] = (uint8_t)(bits>>16);
  }

  // ---- time-dependent biases into registers (global Wy reads are wave-uniform, L2-resident) ----
  float bhreg[40], bvreg[24];
  #pragma unroll
  for (int jj = 0; jj < 40; ++jj) { int j = JLO+jj; bhreg[jj] = (j < NH) ? bh[j] : 0.0f; }
  #pragma unroll
  for (int vv = 0; vv < 24; ++vv) { int v = VLO+vv; bvreg[vv] = (v < NV) ? bv[v] : 0.0f; }
  {
    const float4* l4p = (const float4*)(lstm + (size_t)C * NR);
    for (int rg = 0; rg < NR/4; ++rg) {
      const float4 l4 = l4p[rg];
      #pragma unroll
      for (int jj = 0; jj < 40; ++jj) {
        if (jj < NJ) {
          const float4 wy = *(const float4*)(Wyh + (size_t)(JLO+jj)*NR + rg*4);
          bhreg[jj] += l4.x*wy.x + l4.y*wy.y + l4.z*wy.z + l4.w*wy.w;
        }
      }
      #pragma unroll
      for (int vv = 0; vv < 24; ++vv) {
        if (vv < NVt) {
          const float4 wy = *(const float4*)(Wyv + (size_t)(VLO+vv)*NR + rg*4);
          bvreg[vv] += l4.x*wy.x + l4.y*wy.y + l4.z*wy.z + l4.w*wy.w;
        }
      }
    }
  }
  __syncthreads();   // W, P, V staged

  // ---- CD-k Gibbs chain ----
  float meanv[24];
  #pragma unroll
  for (int vv = 0; vv < 24; ++vv) meanv[vv] = 0.5f;

  for (int t = 0; t < k; ++t) {
    // hidden: mean_h = sigmoid(v@W + bh_t); sample
    {
      float pre[40];
      hidden_matvec(Wl, &Vb32[lane][0], bhreg, pre, JLO, NGH);
      uint32_t b0 = 0, b1 = 0;
      #pragma unroll
      for (int jj = 0; jj < 40; ++jj) {
        if (jj < NJ) {
          const int j = JLO + jj;
          float m = sigmoid_fast(pre[jj]);
          uint32_t seed = (uint32_t)C | ((uint32_t)j << 18) | ((uint32_t)t << 26);
          uint32_t bit = (rng_u(seed) < m) ? 1u : 0u;
          if (jj < 32) b0 |= bit << jj; else b1 |= bit << (jj-32);
        }
      }
      uint8_t* hb = (uint8_t*)&Hb32[lane][0];
      hb[5*w+0] = (uint8_t)b0;        hb[5*w+1] = (uint8_t)(b0>>8);
      hb[5*w+2] = (uint8_t)(b0>>16);  hb[5*w+3] = (uint8_t)(b0>>24);
      hb[5*w+4] = (uint8_t)b1;        // w==3 writes byte 19 = 0 (bits j>=150 clear)
    }
    __syncthreads();
    // visible: mean_v = sigmoid(h@W^T + bv_t); sample
    {
      float pre[24];
      visible_matvec(Wl, &Hb32[lane][0], bvreg, pre, VLO, NVt);
      uint32_t bits = 0;
      #pragma unroll
      for (int vv = 0; vv < 24; ++vv) {
        if (vv < NVt) {
          const int v = VLO + vv;
          float m = sigmoid_fast(pre[vv]);
          meanv[vv] = m;
          uint32_t seed = (uint32_t)C | ((uint32_t)v << 18) | ((uint32_t)t << 26) | (1u << 29);
          if (rng_u(seed) < m) bits |= 1u << vv;
        }
      }
      uint8_t* vb = (uint8_t*)&Vb32[lane][0];
      vb[3*w+0] = (uint8_t)bits; vb[3*w+1] = (uint8_t)(bits>>8); vb[3*w+2] = (uint8_t)(bits>>16);
    }
    __syncthreads();
  }

  // ---- free energies + log-likelihood ----
  float sp_p = 0.0f, sp_v = 0.0f;
  {
    float pre[40];
    hidden_matvec(Wl, &Pb32[lane][0], bhreg, pre, JLO, NGH);
    #pragma unroll
    for (int jj = 0; jj < 40; ++jj)
      if (jj < NJ) sp_p += __logf(1.0f + __expf(pre[jj]));
    hidden_matvec(Wl, &Vb32[lane][0], bhreg, pre, JLO, NGH);
    #pragma unroll
    for (int jj = 0; jj < 40; ++jj)
      if (jj < NJ) sp_v += __logf(1.0f + __expf(pre[jj]));
  }
  float dot_p = 0.0f, dot_v = 0.0f, ll = 0.0f;
  {
    const uint8_t* pb = (const uint8_t*)&Pb32[lane][0];
    const uint8_t* vb = (const uint8_t*)&Vb32[lane][0];
    uint32_t pbits = (uint32_t)pb[3*w] | ((uint32_t)pb[3*w+1] << 8) | ((uint32_t)pb[3*w+2] << 16);
    uint32_t vbits = (uint32_t)vb[3*w] | ((uint32_t)vb[3*w+1] << 8) | ((uint32_t)vb[3*w+2] << 16);
    #pragma unroll
    for (int vv = 0; vv < 24; ++vv) {
      if (vv < NVt) {
        uint32_t p = (pbits >> vv) & 1u;
        float pf = (float)p;
        float vf = (float)((vbits >> vv) & 1u);
        dot_p += pf * bvreg[vv];
        dot_v += vf * bvreg[vv];
        ll += p ? __logf(meanv[vv] + 1e-10f) : __logf(1.0f - meanv[vv] + 1e-10f);
      }
    }
  }
  // cost term per chain: FE(p) - FE(v) = (dot_v + sp_v) - (dot_p + sp_p)
  const float maskc = mask[C];
  float a  = ((dot_v + sp_v) - (dot_p + sp_p)) * maskc;
  float bl = ll * maskc;
  float mm = (w == 0) ? maskc : 0.0f;

  #pragma unroll
  for (int off = 32; off >= 1; off >>= 1) {
    a  += __shfl_down(a,  off);
    bl += __shfl_down(bl, off);
    mm += __shfl_down(mm, off);
  }
  if (lane == 0) { reda[w] = a; redb[w] = bl; redm[w] = mm; }
  __syncthreads();
  if (tid == 0) {
    wsf[(size_t)blockIdx.x*3+0] = reda[0]+reda[1]+reda[2]+reda[3];
    wsf[(size_t)blockIdx.x*3+1] = redb[0]+redb[1]+redb[2]+redb[3];
    wsf[(size_t)blockIdx.x*3+2] = redm[0]+redm[1]+redm[2]+redm[3];
  }
}

__global__ void rbm_finalize_kernel(const float* __restrict__ wsf, float* __restrict__ out)
{
  __shared__ double sh[3][4];
  const int tid = threadIdx.x, lane = tid & 63, w = tid >> 6;
  double sa = 0.0, sb = 0.0, sm = 0.0;
  for (int i = tid; i < NBLK; i += 256) {
    sa += (double)wsf[(size_t)3*i+0];
    sb += (double)wsf[(size_t)3*i+1];
    sm += (double)wsf[(size_t)3*i+2];
  }
  #pragma unroll
  for (int off = 32; off >= 1; off >>= 1) {
    sa += __shfl_down(sa, off);
    sb += __shfl_down(sb, off);
    sm += __shfl_down(sm, off);
  }
  if (lane == 0) { sh[0][w] = sa; sh[1][w] = sb; sh[2][w] = sm; }
  __syncthreads();
  if (tid == 0) {
    double A = sh[0][0]+sh[0][1]+sh[0][2]+sh[0][3];
    double B = sh[1][0]+sh[1][1]+sh[1][2]+sh[1][3];
    double M = sh[2][0]+sh[2][1]+sh[2][2]+sh[2][3];
    out[0] = (float)(A / M);   // cost
    out[1] = (float)(B / M);   // monitor
  }
}

extern "C" void kernel_launch(void* const* d_in, const int* in_sizes, int n_in,
                              void* d_out, int out_size, void* d_ws, size_t ws_size,
                              hipStream_t stream) {
  const float* padded = (const float*)d_in[0];
  const float* mask   = (const float*)d_in[1];
  const float* lstm   = (const float*)d_in[2];
  const float* W      = (const float*)d_in[3];
  const float* bv     = (const float*)d_in[4];
  const float* bh     = (const float*)d_in[5];
  const float* Wyv    = (const float*)d_in[6];
  const float* Wyh    = (const float*)d_in[7];
  const int*   kp     = (const int*)d_in[8];
  float* wsf = (float*)d_ws;
  float* out = (float*)d_out;

  rbm_cdk_kernel<<<NBLK, 256, 0, stream>>>(padded, mask, lstm, W, bv, bh, Wyv, Wyh, kp, wsf);
  rbm_finalize_kernel<<<1, 256, 0, stream>>>(wsf, out);
}

// Round 2
// 3180.248 us; speedup vs baseline: 1.6335x; 1.6335x over previous
//
#include <hip/hip_runtime.h>
#include <stdint.h>

// RBM CD-k (k=5) fused kernel for MI355X — round 2: spill-free restructure.
// Block = 512 threads (8 waves) = 64 chains (lane = chain), units split 8-ways:
// 20 hidden (padded; 150 real) / 11 visible units per wave-thread.
// W staged in LDS f32 [88][160] (cols >=150 zero); W reads are wave-uniform
// broadcast float4. Binary states: one u32 word per (chain, wave) in LDS,
// stride 9 dwords (bank-conflict-free). FE(padded) folded into iter 0;
// log-likelihood folded into iter k-1 (no meanv array).
// RNG: lowbias32 hash of unique (chain,unit,iter,phase) counters — outputs are
// means over 262144 chains, so any iid-uniform stream is statistically
// equivalent to jax threefry here (round-1 absmax 4.9e-4 confirms).

#define NV 88
#define NH 150
#define NHP 160      // hidden padded to 8*20
#define NR 100
#define NBT (128*2048)
#define CPB 64       // chains per block
#define NBLK (NBT/CPB)   // 4096
#define JW 20        // hidden units per wave (padded)
#define VWU 11       // visible units per wave (88 = 8*11)

__device__ __forceinline__ uint32_t hash32(uint32_t x) {
  x ^= x >> 16; x *= 0x7feb352dU;
  x ^= x >> 15; x *= 0x846ca68bU;
  x ^= x >> 16;
  return x;
}
__device__ __forceinline__ float rng_u(uint32_t seed) {
  return (float)(hash32(seed) >> 8) * (1.0f/16777216.0f);
}
__device__ __forceinline__ float sigmoid_fast(float x) {
  return __fdividef(1.0f, 1.0f + __expf(-x));
}

// pre[0..19] = bhreg + sum_i vbit_i * W[i][JLO..JLO+20)
__device__ __forceinline__ void hidden_matvec(
    const float (*Wl)[NHP], const uint32_t* vwords,
    const float* bhreg, float* pre, int JLO)
{
  #pragma unroll
  for (int jj = 0; jj < JW; ++jj) pre[jj] = bhreg[jj];
  for (int wi = 0; wi < 8; ++wi) {
    const uint32_t word = vwords[wi];          // bits for visible units 11*wi..+10
    #pragma unroll
    for (int b = 0; b < VWU; ++b) {
      const float f = (float)((word >> b) & 1u);
      const float* row = &Wl[wi*VWU + b][JLO];
      #pragma unroll
      for (int g = 0; g < 5; ++g) {
        const float4 w4 = *(const float4*)(row + 4*g);
        pre[4*g+0] = fmaf(f, w4.x, pre[4*g+0]);
        pre[4*g+1] = fmaf(f, w4.y, pre[4*g+1]);
        pre[4*g+2] = fmaf(f, w4.z, pre[4*g+2]);
        pre[4*g+3] = fmaf(f, w4.w, pre[4*g+3]);
      }
    }
  }
}

// pre[0..10] = bvreg + sum_j hbit_j * W[VLO+vv][j]   (j over 160 padded, pads are 0)
__device__ __forceinline__ void visible_matvec(
    const float (*Wl)[NHP], const uint32_t* hwords,
    const float* bvreg, float* pre, int VLO)
{
  #pragma unroll
  for (int vv = 0; vv < VWU; ++vv) pre[vv] = bvreg[vv];
  for (int wi = 0; wi < 8; ++wi) {
    const uint32_t word = hwords[wi];          // bits for hidden units 20*wi..+19
    float h[JW];
    #pragma unroll
    for (int b = 0; b < JW; ++b) h[b] = (float)((word >> b) & 1u);
    #pragma unroll
    for (int vv = 0; vv < VWU; ++vv) {
      const float* row = &Wl[VLO + vv][wi*JW];
      float acc = pre[vv];
      #pragma unroll
      for (int g = 0; g < 5; ++g) {
        const float4 w4 = *(const float4*)(row + 4*g);
        acc = fmaf(h[4*g+0], w4.x, acc);
        acc = fmaf(h[4*g+1], w4.y, acc);
        acc = fmaf(h[4*g+2], w4.z, acc);
        acc = fmaf(h[4*g+3], w4.w, acc);
      }
      pre[vv] = acc;
    }
  }
}

__global__ __launch_bounds__(512, 4) void rbm_cdk_kernel(
    const float* __restrict__ padded, const float* __restrict__ mask,
    const float* __restrict__ lstm,   const float* __restrict__ W,
    const float* __restrict__ bv,     const float* __restrict__ bh,
    const float* __restrict__ Wyv,    const float* __restrict__ Wyh,
    const int*  __restrict__ kptr,    float* __restrict__ wsf)
{
  __shared__ __align__(16) float Wl[NV][NHP];   // 56.3 KB
  __shared__ uint32_t Hw[CPB][9];               // hidden bit words (stride 9: no conflicts)
  __shared__ uint32_t Vw[CPB][9];
  __shared__ uint32_t Pw[CPB][9];
  __shared__ float reda[8], redb[8], redm[8];

  const int tid  = threadIdx.x;
  const int lane = tid & 63;
  const int w    = tid >> 6;
  const int C    = blockIdx.x * CPB + lane;     // global chain id < 2^18
  const int k    = kptr[0];

  const int JLO = w * JW;                       // hidden slice [JLO, JLO+20)
  const int NJ  = (w == 7) ? 10 : JW;           // real hidden units in slice
  const int VLO = w * VWU;                      // visible slice [VLO, VLO+11)

  // ---- stage W (zero-pad cols 150..159) ----
  for (int idx = tid; idx < NV*NHP; idx += 512) {
    int r = idx / NHP, c = idx - r*NHP;
    Wl[r][c] = (c < NH) ? W[r*NH + c] : 0.0f;
  }

  // ---- stage padded bits; init V = P ----
  {
    uint32_t bits = 0;
    const float* p = padded + (size_t)C * NV + VLO;
    #pragma unroll
    for (int vv = 0; vv < VWU; ++vv)
      bits |= (p[vv] > 0.5f ? 1u : 0u) << vv;
    Pw[lane][w] = bits;
    Vw[lane][w] = bits;
  }

  // ---- time-dependent biases into registers ----
  float bhreg[JW], bvreg[VWU];
  #pragma unroll
  for (int jj = 0; jj < JW; ++jj) bhreg[jj] = (jj < NJ) ? bh[JLO + jj] : 0.0f;
  #pragma unroll
  for (int vv = 0; vv < VWU; ++vv) bvreg[vv] = bv[VLO + vv];
  {
    const float4* l4p = (const float4*)(lstm + (size_t)C * NR);
    for (int rg = 0; rg < NR/4; ++rg) {
      const float4 l4 = l4p[rg];
      #pragma unroll
      for (int jj = 0; jj < JW; ++jj) {
        if (jj < NJ) {
          const float4 wy = *(const float4*)(Wyh + (size_t)(JLO + jj)*NR + 4*rg);
          bhreg[jj] = fmaf(l4.x, wy.x, fmaf(l4.y, wy.y, fmaf(l4.z, wy.z, fmaf(l4.w, wy.w, bhreg[jj]))));
        }
      }
      #pragma unroll
      for (int vv = 0; vv < VWU; ++vv) {
        const float4 wy = *(const float4*)(Wyv + (size_t)(VLO + vv)*NR + 4*rg);
        bvreg[vv] = fmaf(l4.x, wy.x, fmaf(l4.y, wy.y, fmaf(l4.z, wy.z, fmaf(l4.w, wy.w, bvreg[vv]))));
      }
    }
  }
  __syncthreads();   // W, P, V staged

  // ---- CD-k Gibbs chain (FE(p) folded into t==0, ll folded into t==k-1) ----
  float sp_p = 0.0f, sp_v = 0.0f, llv = 0.0f;

  for (int t = 0; t < k; ++t) {
    // hidden: pre = v@W + bh_t ; sample
    {
      float pre[JW];
      hidden_matvec(Wl, &Vw[lane][0], bhreg, pre, JLO);
      if (t == 0) {   // v_sample == padded here: free_energy(padded) softplus term
        #pragma unroll
        for (int jj = 0; jj < JW; ++jj)
          if (jj < NJ) sp_p += __logf(1.0f + __expf(pre[jj]));
      }
      uint32_t hb = 0;
      #pragma unroll
      for (int jj = 0; jj < JW; ++jj) {
        if (jj < NJ) {
          const float m = sigmoid_fast(pre[jj]);
          const uint32_t seed = (uint32_t)C | ((uint32_t)(JLO + jj) << 18) | ((uint32_t)t << 26);
          hb |= (rng_u(seed) < m ? 1u : 0u) << jj;
        }
      }
      Hw[lane][w] = hb;
    }
    __syncthreads();
    // visible: pre = h@W^T + bv_t ; (ll at t==k-1) ; sample
    {
      float pre[VWU];
      visible_matvec(Wl, &Hw[lane][0], bvreg, pre, VLO);
      const uint32_t pbits = Pw[lane][w];
      const bool last = (t == k - 1);
      uint32_t vb = 0;
      #pragma unroll
      for (int vv = 0; vv < VWU; ++vv) {
        const float m = sigmoid_fast(pre[vv]);
        if (last) {
          llv += ((pbits >> vv) & 1u) ? __logf(m + 1e-10f) : __logf(1.0f - m + 1e-10f);
        }
        const uint32_t seed = (uint32_t)C | ((uint32_t)(VLO + vv) << 18) | ((uint32_t)t << 26) | (1u << 29);
        vb |= (rng_u(seed) < m ? 1u : 0u) << vv;
      }
      Vw[lane][w] = vb;
    }
    __syncthreads();
  }

  // ---- free energy of final v_sample ----
  {
    float pre[JW];
    hidden_matvec(Wl, &Vw[lane][0], bhreg, pre, JLO);
    #pragma unroll
    for (int jj = 0; jj < JW; ++jj)
      if (jj < NJ) sp_v += __logf(1.0f + __expf(pre[jj]));
  }
  float dot_p = 0.0f, dot_v = 0.0f;
  {
    const uint32_t pbits = Pw[lane][w];
    const uint32_t vbits = Vw[lane][w];
    #pragma unroll
    for (int vv = 0; vv < VWU; ++vv) {
      dot_p += ((pbits >> vv) & 1u) ? bvreg[vv] : 0.0f;
      dot_v += ((vbits >> vv) & 1u) ? bvreg[vv] : 0.0f;
    }
  }

  // cost term per chain: FE(p) - FE(v) = (dot_v + sp_v) - (dot_p + sp_p)
  const float maskc = mask[C];
  float a  = ((dot_v + sp_v) - (dot_p + sp_p)) * maskc;
  float bl = llv * maskc;
  float mm = (w == 0) ? maskc : 0.0f;

  #pragma unroll
  for (int off = 32; off >= 1; off >>= 1) {
    a  += __shfl_down(a,  off);
    bl += __shfl_down(bl, off);
    mm += __shfl_down(mm, off);
  }
  if (lane == 0) { reda[w] = a; redb[w] = bl; redm[w] = mm; }
  __syncthreads();
  if (tid == 0) {
    float sa = 0.f, sb = 0.f, sm = 0.f;
    #pragma unroll
    for (int i = 0; i < 8; ++i) { sa += reda[i]; sb += redb[i]; sm += redm[i]; }
    wsf[(size_t)blockIdx.x*3+0] = sa;
    wsf[(size_t)blockIdx.x*3+1] = sb;
    wsf[(size_t)blockIdx.x*3+2] = sm;
  }
}

__global__ void rbm_finalize_kernel(const float* __restrict__ wsf, float* __restrict__ out)
{
  __shared__ double sh[3][4];
  const int tid = threadIdx.x, lane = tid & 63, w = tid >> 6;
  double sa = 0.0, sb = 0.0, sm = 0.0;
  for (int i = tid; i < NBLK; i += 256) {
    sa += (double)wsf[(size_t)3*i+0];
    sb += (double)wsf[(size_t)3*i+1];
    sm += (double)wsf[(size_t)3*i+2];
  }
  #pragma unroll
  for (int off = 32; off >= 1; off >>= 1) {
    sa += __shfl_down(sa, off);
    sb += __shfl_down(sb, off);
    sm += __shfl_down(sm, off);
  }
  if (lane == 0) { sh[0][w] = sa; sh[1][w] = sb; sh[2][w] = sm; }
  __syncthreads();
  if (tid == 0) {
    double A = sh[0][0]+sh[0][1]+sh[0][2]+sh[0][3];
    double B = sh[1][0]+sh[1][1]+sh[1][2]+sh[1][3];
    double M = sh[2][0]+sh[2][1]+sh[2][2]+sh[2][3];
    out[0] = (float)(A / M);   // cost
    out[1] = (float)(B / M);   // monitor
  }
}

extern "C" void kernel_launch(void* const* d_in, const int* in_sizes, int n_in,
                              void* d_out, int out_size, void* d_ws, size_t ws_size,
                              hipStream_t stream) {
  const float* padded = (const float*)d_in[0];
  const float* mask   = (const float*)d_in[1];
  const float* lstm   = (const float*)d_in[2];
  const float* W      = (const float*)d_in[3];
  const float* bv     = (const float*)d_in[4];
  const float* bh     = (const float*)d_in[5];
  const float* Wyv    = (const float*)d_in[6];
  const float* Wyh    = (const float*)d_in[7];
  const int*   kp     = (const int*)d_in[8];
  float* wsf = (float*)d_ws;
  float* out = (float*)d_out;

  rbm_cdk_kernel<<<NBLK, 512, 0, stream>>>(padded, mask, lstm, W, bv, bh, Wyv, Wyh, kp, wsf);
  rbm_finalize_kernel<<<1, 256, 0, stream>>>(wsf, out);
}

// Round 3
// 807.529 us; speedup vs baseline: 6.4331x; 3.9382x over previous
//
#include <hip/hip_runtime.h>
#include <stdint.h>

// RBM CD-k fused MFMA kernel for MI355X (round 3).
// Block = 128 chains, 8 waves; wave m owns chains [m*16, m*16+16) (its M-tile).
// Gibbs matvecs are mfma_f32_16x16x32_bf16 GEMMs; W in LDS bf16 (both
// orientations); time-dependent biases computed once per block via MFMA and
// held in registers as C-fragments (they init every Gibbs accumulator).
// Sampled states written as bf16 0/1 to per-wave-private LDS rows -> the
// Gibbs loop needs NO __syncthreads. Setup arrays overlay W/H LDS (union).
// RNG: lowbias32 hash of (chain,unit,iter,phase) - statistically equivalent
// to jax threefry for these chain-averaged scalars (validated rounds 1-2).

#define NV 88
#define NH 150
#define NR 100
#define NBT (128*2048)
#define CPB 128
#define NBLK (NBT/CPB)   // 2048

// LDS row strides in ushort units (chosen: stride*2B/4 mod 32 gives >=8
// distinct bank groups -> <=2-way conflict on b128 fragment reads)
#define WSTR 168   // Wlds  [96][168]  (visible-GEMM B^T = W row-major)
#define TSTR 104   // WTl   [160][104] (hidden-GEMM  B^T = W^T)
#define HSTR 168   // Hl    [128][168]
#define VSTR 104   // Vl    [128][104]
#define LSTR 136   // lstmC/WyhT/WyvT [*][136]

// byte offsets into the shared arena
#define OFF_W     0
#define OFF_WT    32256     // 96*168*2
#define OFF_H     65536     // +160*104*2
#define OFF_V     108544    // +128*168*2
#define OFF_PB    135168    // +128*104*2
#define OFF_RED   137216    // +128*4*4
#define SMEM_SZ   137312    // +8*3*4
// setup overlay (dies after bias GEMM; ends 104448 <= OFF_V, so V/Pb safe)
#define OFF_LSTM  0
#define OFF_WYH   34816     // 128*136*2
#define OFF_WYV   78336     // +160*136*2

typedef __bf16 bf16x8 __attribute__((ext_vector_type(8)));
typedef float  f32x4  __attribute__((ext_vector_type(4)));

__device__ __forceinline__ uint32_t hash32(uint32_t x) {
  x ^= x >> 16; x *= 0x7feb352dU;
  x ^= x >> 15; x *= 0x846ca68bU;
  x ^= x >> 16;
  return x;
}
__device__ __forceinline__ float rng_u(uint32_t seed) {
  return (float)(hash32(seed) >> 8) * (1.0f/16777216.0f);
}
__device__ __forceinline__ float sigmoid_fast(float x) {
  return __fdividef(1.0f, 1.0f + __expf(-x));
}
__device__ __forceinline__ unsigned short f2bf(float f) {   // RNE f32->bf16
  uint32_t u = __float_as_uint(f);
  return (unsigned short)((u + 0x7FFFu + ((u >> 16) & 1u)) >> 16);
}

__global__ __launch_bounds__(512, 2) void rbm_cdk_mfma(
    const float* __restrict__ padded, const float* __restrict__ mask,
    const float* __restrict__ lstm,   const float* __restrict__ W,
    const float* __restrict__ bv,     const float* __restrict__ bh,
    const float* __restrict__ Wyv,    const float* __restrict__ Wyh,
    const int*  __restrict__ kptr,    float* __restrict__ wsf)
{
  __shared__ __align__(16) unsigned char smem[SMEM_SZ];
  unsigned short* Wl  = (unsigned short*)(smem + OFF_W);
  unsigned short* WTl = (unsigned short*)(smem + OFF_WT);
  unsigned short* Hl  = (unsigned short*)(smem + OFF_H);
  unsigned short* Vl  = (unsigned short*)(smem + OFF_V);
  uint32_t*       Pb  = (uint32_t*)      (smem + OFF_PB);
  float*          red = (float*)         (smem + OFF_RED);
  unsigned short* Ls  = (unsigned short*)(smem + OFF_LSTM);
  unsigned short* Yh  = (unsigned short*)(smem + OFF_WYH);
  unsigned short* Yv  = (unsigned short*)(smem + OFF_WYV);

  const int tid = threadIdx.x;
  const int l   = tid & 63;
  const int w   = tid >> 6;
  const int Cb  = blockIdx.x * CPB;
  const int k   = kptr[0];

  const int col = l & 15;          // B column within 16-tile / C col / A row sel
  const int kb  = (l >> 4) * 8;    // K-block element offset for A/B frags
  const int c0  = w*16 + (l >> 4) * 4;   // C-frag local chain base (rows c0..c0+3)
  const int arw = w*16 + col;            // A-frag local chain row

  // ================= Phase 1: stage lstmC / WyhT / WyvT / V =================
  for (int i = tid; i < CPB*LSTR; i += 512) {
    int r = i / LSTR, c = i - r*LSTR;
    unsigned short v = 0;
    if (c < NR) v = f2bf(lstm[(size_t)(Cb + r)*NR + c]);
    else if (c == NR) v = 0x3F80;                        // the "1" for bias fold
    Ls[i] = v;
  }
  for (int i = tid; i < 160*LSTR; i += 512) {
    int r = i / LSTR, c = i - r*LSTR;
    unsigned short v = 0;
    if (r < NH) { if (c < NR) v = f2bf(Wyh[r*NR + c]); else if (c == NR) v = f2bf(bh[r]); }
    Yh[i] = v;
  }
  for (int i = tid; i < 96*LSTR; i += 512) {
    int r = i / LSTR, c = i - r*LSTR;
    unsigned short v = 0;
    if (r < NV) { if (c < NR) v = f2bf(Wyv[r*NR + c]); else if (c == NR) v = f2bf(bv[r]); }
    Yv[i] = v;
  }
  for (int i = tid; i < CPB*VSTR; i += 512) {
    int r = i / VSTR, c = i - r*VSTR;
    unsigned short v = 0;
    if (c < NV) v = (padded[(size_t)(Cb + r)*NV + c] > 0.5f) ? 0x3F80 : 0;
    Vl[i] = v;
  }
  __syncthreads();

  // ======== Phase 2: bias GEMMs -> C-fragments kept in registers ===========
  // bh_t[c][j] = sum_r lstm[c][r]*Wyh[j][r] + bh[j]   (K=128 incl. 1-trick)
  f32x4 bhF[10], bvF[6];
  {
    bf16x8 al[4];
    #pragma unroll
    for (int ks = 0; ks < 4; ++ks)
      al[ks] = *(const bf16x8*)(Ls + arw*LSTR + kb + 32*ks);
    #pragma unroll
    for (int n = 0; n < 10; ++n) {
      f32x4 acc = {0.f, 0.f, 0.f, 0.f};
      #pragma unroll
      for (int ks = 0; ks < 4; ++ks) {
        bf16x8 b = *(const bf16x8*)(Yh + (16*n + col)*LSTR + kb + 32*ks);
        acc = __builtin_amdgcn_mfma_f32_16x16x32_bf16(al[ks], b, acc, 0, 0, 0);
      }
      bhF[n] = acc;
    }
    #pragma unroll
    for (int n = 0; n < 6; ++n) {
      f32x4 acc = {0.f, 0.f, 0.f, 0.f};
      #pragma unroll
      for (int ks = 0; ks < 4; ++ks) {
        bf16x8 b = *(const bf16x8*)(Yv + (16*n + col)*LSTR + kb + 32*ks);
        acc = __builtin_amdgcn_mfma_f32_16x16x32_bf16(al[ks], b, acc, 0, 0, 0);
      }
      bvF[n] = acc;
    }
  }
  __syncthreads();   // all waves done reading setup arrays

  // ============ Phase 3: stage W (both orientations) + P bits ==============
  for (int i = tid; i < 96*WSTR; i += 512) {
    int r = i / WSTR, c = i - r*WSTR;
    Wl[i] = (r < NV && c < NH) ? f2bf(W[r*NH + c]) : (unsigned short)0;
  }
  for (int i = tid; i < 160*TSTR; i += 512) {
    int r = i / TSTR, c = i - r*TSTR;
    WTl[i] = (r < NH && c < NV) ? f2bf(W[c*NH + r]) : (unsigned short)0;
  }
  {  // padded bits from V LDS (512 threads = 128 rows x 4 words exactly)
    int r = tid >> 2, word = tid & 3;
    uint32_t bits = 0;
    for (int b = 0; b < 32; ++b) {
      int v = word*32 + b;
      if (v < NV && Vl[r*VSTR + v] != 0) bits |= 1u << b;
    }
    Pb[tid] = bits;
  }
  __syncthreads();

  // ================= Phase 4: Gibbs chain (barrier-free) ====================
  float sp_p[4] = {0,0,0,0}, llv[4] = {0,0,0,0};
  float dpp[4]  = {0,0,0,0}, dvv[4] = {0,0,0,0};

  for (int t = 0; t < k; ++t) {
    // ---- hidden: pre = V@W + bh_t ; sample h ----
    {
      bf16x8 av[3];
      #pragma unroll
      for (int ks = 0; ks < 3; ++ks)
        av[ks] = *(const bf16x8*)(Vl + arw*VSTR + kb + 32*ks);
      const bool first = (t == 0);
      #pragma unroll
      for (int n = 0; n < 10; ++n) {
        f32x4 acc = bhF[n];
        #pragma unroll
        for (int ks = 0; ks < 3; ++ks) {
          bf16x8 b = *(const bf16x8*)(WTl + (16*n + col)*TSTR + kb + 32*ks);
          acc = __builtin_amdgcn_mfma_f32_16x16x32_bf16(av[ks], b, acc, 0, 0, 0);
        }
        const int j = 16*n + col;
        const bool real = (j < NH);
        #pragma unroll
        for (int r = 0; r < 4; ++r) {
          const float pre = acc[r];
          const float mh  = sigmoid_fast(pre);
          if (first && real) sp_p[r] += __logf(1.0f + __expf(pre));
          const uint32_t seed = (uint32_t)(Cb + c0 + r) | ((uint32_t)j << 18) | ((uint32_t)t << 26);
          const unsigned short hv = (real && (rng_u(seed) < mh)) ? (unsigned short)0x3F80 : (unsigned short)0;
          Hl[(c0 + r)*HSTR + j] = hv;
        }
      }
    }
    // ---- visible: pre = H@W^T + bv_t ; (ll/dot at t==k-1) ; sample v ----
    {
      bf16x8 ah[5];
      #pragma unroll
      for (int ks = 0; ks < 5; ++ks)
        ah[ks] = *(const bf16x8*)(Hl + arw*HSTR + kb + 32*ks);
      const bool last = (t == k-1);
      #pragma unroll
      for (int n = 0; n < 6; ++n) {
        f32x4 acc = bvF[n];
        #pragma unroll
        for (int ks = 0; ks < 5; ++ks) {
          bf16x8 b = *(const bf16x8*)(Wl + (16*n + col)*WSTR + kb + 32*ks);
          acc = __builtin_amdgcn_mfma_f32_16x16x32_bf16(ah[ks], b, acc, 0, 0, 0);
        }
        const int v = 16*n + col;
        const bool real = (v < NV);
        #pragma unroll
        for (int r = 0; r < 4; ++r) {
          const float mv = sigmoid_fast(acc[r]);
          const uint32_t seed = (uint32_t)(Cb + c0 + r) | ((uint32_t)v << 18) | ((uint32_t)t << 26) | (1u << 29);
          const uint32_t bit = (real && (rng_u(seed) < mv)) ? 1u : 0u;
          if (last && real) {
            const uint32_t pbit = (Pb[(c0 + r)*4 + (v >> 5)] >> (v & 31)) & 1u;
            llv[r] += pbit ? __logf(mv + 1e-10f) : __logf(1.0f - mv + 1e-10f);
            const float bvt = bvF[n][r];
            dpp[r] += pbit ? bvt : 0.0f;
            dvv[r] += bit  ? bvt : 0.0f;
          }
          Vl[(c0 + r)*VSTR + v] = bit ? (unsigned short)0x3F80 : (unsigned short)0;
        }
      }
    }
  }

  // ---- final hidden GEMM on v_sample: softplus term of FE(v) ----
  float sp_v[4] = {0,0,0,0};
  {
    bf16x8 av[3];
    #pragma unroll
    for (int ks = 0; ks < 3; ++ks)
      av[ks] = *(const bf16x8*)(Vl + arw*VSTR + kb + 32*ks);
    #pragma unroll
    for (int n = 0; n < 10; ++n) {
      f32x4 acc = bhF[n];
      #pragma unroll
      for (int ks = 0; ks < 3; ++ks) {
        bf16x8 b = *(const bf16x8*)(WTl + (16*n + col)*TSTR + kb + 32*ks);
        acc = __builtin_amdgcn_mfma_f32_16x16x32_bf16(av[ks], b, acc, 0, 0, 0);
      }
      const int j = 16*n + col;
      if (j < NH) {
        #pragma unroll
        for (int r = 0; r < 4; ++r)
          sp_v[r] += __logf(1.0f + __expf(acc[r]));
      }
    }
  }

  // ================= reduction =================
  // per chain: cost = (dot_v + sp_v) - (dot_p + sp_p); ll
  float ca[4];
  #pragma unroll
  for (int r = 0; r < 4; ++r)
    ca[r] = (dvv[r] + sp_v[r]) - (dpp[r] + sp_p[r]);
  #pragma unroll
  for (int off = 1; off <= 8; off <<= 1) {
    #pragma unroll
    for (int r = 0; r < 4; ++r) {
      ca[r]  += __shfl_xor(ca[r],  off);
      llv[r] += __shfl_xor(llv[r], off);
    }
  }
  float a = 0.f, b = 0.f, mm = 0.f;
  if (col == 0) {   // lanes 0,16,32,48 hold complete sums for chains c0..c0+3
    const float4 mk = *(const float4*)(mask + Cb + c0);
    a  = ca[0]*mk.x  + ca[1]*mk.y  + ca[2]*mk.z  + ca[3]*mk.w;
    b  = llv[0]*mk.x + llv[1]*mk.y + llv[2]*mk.z + llv[3]*mk.w;
    mm = mk.x + mk.y + mk.z + mk.w;
  }
  a  += __shfl_xor(a, 16);  a  += __shfl_xor(a, 32);
  b  += __shfl_xor(b, 16);  b  += __shfl_xor(b, 32);
  mm += __shfl_xor(mm, 16); mm += __shfl_xor(mm, 32);
  if (l == 0) { red[w*3+0] = a; red[w*3+1] = b; red[w*3+2] = mm; }
  __syncthreads();
  if (tid == 0) {
    float sa = 0.f, sb = 0.f, sm = 0.f;
    #pragma unroll
    for (int i = 0; i < 8; ++i) { sa += red[i*3]; sb += red[i*3+1]; sm += red[i*3+2]; }
    wsf[(size_t)blockIdx.x*3+0] = sa;
    wsf[(size_t)blockIdx.x*3+1] = sb;
    wsf[(size_t)blockIdx.x*3+2] = sm;
  }
}

__global__ void rbm_finalize_kernel(const float* __restrict__ wsf, float* __restrict__ out)
{
  __shared__ double sh[3][4];
  const int tid = threadIdx.x, lane = tid & 63, w = tid >> 6;
  double sa = 0.0, sb = 0.0, sm = 0.0;
  for (int i = tid; i < NBLK; i += 256) {
    sa += (double)wsf[(size_t)3*i+0];
    sb += (double)wsf[(size_t)3*i+1];
    sm += (double)wsf[(size_t)3*i+2];
  }
  #pragma unroll
  for (int off = 32; off >= 1; off >>= 1) {
    sa += __shfl_down(sa, off);
    sb += __shfl_down(sb, off);
    sm += __shfl_down(sm, off);
  }
  if (lane == 0) { sh[0][w] = sa; sh[1][w] = sb; sh[2][w] = sm; }
  __syncthreads();
  if (tid == 0) {
    double A = sh[0][0]+sh[0][1]+sh[0][2]+sh[0][3];
    double B = sh[1][0]+sh[1][1]+sh[1][2]+sh[1][3];
    double M = sh[2][0]+sh[2][1]+sh[2][2]+sh[2][3];
    out[0] = (float)(A / M);   // cost
    out[1] = (float)(B / M);   // monitor
  }
}

extern "C" void kernel_launch(void* const* d_in, const int* in_sizes, int n_in,
                              void* d_out, int out_size, void* d_ws, size_t ws_size,
                              hipStream_t stream) {
  const float* padded = (const float*)d_in[0];
  const float* mask   = (const float*)d_in[1];
  const float* lstm   = (const float*)d_in[2];
  const float* W      = (const float*)d_in[3];
  const float* bv     = (const float*)d_in[4];
  const float* bh     = (const float*)d_in[5];
  const float* Wyv    = (const float*)d_in[6];
  const float* Wyh    = (const float*)d_in[7];
  const int*   kp     = (const int*)d_in[8];
  float* wsf = (float*)d_ws;
  float* out = (float*)d_out;

  rbm_cdk_mfma<<<NBLK, 512, 0, stream>>>(padded, mask, lstm, W, bv, bh, Wyv, Wyh, kp, wsf);
  rbm_finalize_kernel<<<1, 256, 0, stream>>>(wsf, out);
}